// Round 6
// baseline (180.706 us; speedup 1.0000x reference)
//
#include <hip/hip_runtime.h>
#include <hip/hip_bf16.h>

#define NN 512
#define NSTEPS 5
#define FSTR 32   // flag stride in ints: 128 B/flag, one line each

typedef __attribute__((ext_vector_type(8))) short short8;
typedef __attribute__((ext_vector_type(4))) float floatx4;

static __device__ __forceinline__ unsigned short f2bf(float f) {
    union { float f; unsigned u; } x; x.f = f;
    unsigned r = x.u + 0x7fffu + ((x.u >> 16) & 1u);
    return (unsigned short)(r >> 16);
}

static __device__ __forceinline__ unsigned pk2bf(float a, float b) {
    __hip_bfloat162 h = __float22bfloat162_rn(make_float2(a, b));
    return *reinterpret_cast<unsigned*>(&h);
}

// ============================================================================
// Barrier-free fused kernel, v4: 512 blocks x 256 threads, ONE node per block
// -> 2 co-resident blocks/CU (VGPR<=256 via launch_bounds, ~10KB LDS), so
// cross-block TLP covers the poll/IF$-latency/GRU-tail stalls that capped v3
// (1 block/CU) at 90us. Flag dataflow identical to the verified v3:
//   producer: agent-scope stores of its 64-float a-row, vmcnt(0), flag[j]=s.
//   consumer: parallel-polls the 8 flags for its rows (one round-trip when
//             already set), then plain cached vector loads (panel buffer s is
//             write-once-then-read-only; 5 distinct buffers, no reuse hazard).
// Plain launch (cooperative launch costs ~32us extra; kernel-boundary sync
// costs ~26us/step; cg::sync ~27us; custom tree barrier ~60us -- all measured).
// ============================================================================
__global__ __launch_bounds__(256, 2) void fused4_kernel(
    const float* __restrict__ J, const float* __restrict__ b,
    const float* __restrict__ W1, const float* __restrict__ b1,
    const float* __restrict__ W2, const float* __restrict__ b2,
    const float* __restrict__ W3, const float* __restrict__ b3,
    const float* __restrict__ W_ih, const float* __restrict__ b_ih,
    const float* __restrict__ W_hh, const float* __restrict__ b_hh,
    const float* __restrict__ Wr1, const float* __restrict__ br1,
    const float* __restrict__ Wr2, const float* __restrict__ br2,
    const float* __restrict__ Wr3, const float* __restrict__ br3,
    float* __restrict__ aP, int* __restrict__ flag,
    float* __restrict__ out)
{
    const int j   = blockIdx.x;
    const int tid = threadIdx.x;
    const int l = tid & 63, w = tid >> 6;
    const int m = l & 15,  q = l >> 4;

    __shared__ float smW1hi[64][16], smW1hj[64][16];
    __shared__ float smC[64], smAbias[64], smCbias[64];
    __shared__ float smWave[4][64], smMacc[64];
    __shared__ float smGin[48], smGi[48], smGh[48];
    __shared__ float smH[16], smY[64], smR[2];

    // Drop stale clean L1/L2 lines of the workspace (harness poison-fill).
    __builtin_amdgcn_fence(__ATOMIC_ACQUIRE, "agent");

    // ---- one-time init: weights to LDS, publish a^1 (h0=0 -> bias-only) ----
    const float bj = b[j];
    if (tid < 64) {
        const float* w1r = W1 + tid*35;
        #pragma unroll
        for (int s0 = 0; s0 < 16; ++s0) {
            smW1hi[tid][s0] = w1r[s0];
            smW1hj[tid][s0] = w1r[16 + s0];
        }
        float ab = bj * w1r[33];
        smAbias[tid] = ab;
        float cb = bj * w1r[34] + b1[tid];
        smCbias[tid] = cb;
        smC[tid] = cb;                     // h0 = 0 -> c0 bias-only
        __hip_atomic_store(&aP[32768 + j*64 + tid], ab,
                           __ATOMIC_RELAXED, __HIP_MEMORY_SCOPE_AGENT);
    }
    if (tid < 64) {    // whole wave 0: wave-uniform vmcnt, then set flag
        asm volatile("s_waitcnt vmcnt(0)" ::: "memory");
        if (tid == 0)
            __hip_atomic_store(&flag[j*FSTR], 1,
                               __ATOMIC_RELAXED, __HIP_MEMORY_SCOPE_AGENT);
    }
    if (tid >= 64 && tid < 80) smH[tid - 64] = 0.f;

    // J column for this node (i = w*128 + c8*16 + m), once
    float Jr[8];
    #pragma unroll
    for (int c8 = 0; c8 < 8; ++c8)
        Jr[c8] = J[(w*128 + c8*16 + m)*512 + j];

    // wJ vectors for this lane's o-set
    floatx4 wva, wvb, wvc, wvd;
    #pragma unroll
    for (int e = 0; e < 4; ++e) {
        wva[e] = W1[(q*8 + e)*35 + 32];
        wvb[e] = W1[(q*8 + 4 + e)*35 + 32];
        wvc[e] = W1[(32 + q*8 + e)*35 + 32];
        wvd[e] = W1[(32 + q*8 + 4 + e)*35 + 32];
    }

    // W2 B-fragments, in-register, once. B[k][n] = W2[n][k]
    short8 bfw[4][2];
    #pragma unroll
    for (int nt = 0; nt < 4; ++nt) {
        #pragma unroll
        for (int ks = 0; ks < 2; ++ks) {
            union { short8 s; unsigned short us[8]; } tpk;
            int n = nt*16 + m;
            #pragma unroll
            for (int jj = 0; jj < 8; ++jj)
                tpk.us[jj] = f2bf(W2[n*64 + ks*32 + q*8 + jj]);
            bfw[nt][ks] = tpk.s;
        }
    }
    float b2n[4];
    #pragma unroll
    for (int nt = 0; nt < 4; ++nt) b2n[nt] = b2[nt*16 + m];

    __syncthreads();   // smC / smW1 / smH ready

    for (int t = 0; t < NSTEPS; ++t) {
        const int last = (t == NSTEPS - 1);
        const int s = t + 1;               // panel generation consumed now

        floatx4 cva, cvb, cvc, cvd;
        #pragma unroll
        for (int e = 0; e < 4; ++e) {
            cva[e] = smC[q*8 + e];
            cvb[e] = smC[q*8 + 4 + e];
            cvc[e] = smC[32 + q*8 + e];
            cvd[e] = smC[32 + q*8 + 4 + e];
        }

        // wait for the 8 rows this lane reads -- PARALLEL poll
        {
            const int rbase = w*128 + m;
            for (;;) {
                int f0 = __hip_atomic_load(&flag[(rbase +   0)*FSTR], __ATOMIC_RELAXED, __HIP_MEMORY_SCOPE_AGENT);
                int f1 = __hip_atomic_load(&flag[(rbase +  16)*FSTR], __ATOMIC_RELAXED, __HIP_MEMORY_SCOPE_AGENT);
                int f2 = __hip_atomic_load(&flag[(rbase +  32)*FSTR], __ATOMIC_RELAXED, __HIP_MEMORY_SCOPE_AGENT);
                int f3 = __hip_atomic_load(&flag[(rbase +  48)*FSTR], __ATOMIC_RELAXED, __HIP_MEMORY_SCOPE_AGENT);
                int f4 = __hip_atomic_load(&flag[(rbase +  64)*FSTR], __ATOMIC_RELAXED, __HIP_MEMORY_SCOPE_AGENT);
                int f5 = __hip_atomic_load(&flag[(rbase +  80)*FSTR], __ATOMIC_RELAXED, __HIP_MEMORY_SCOPE_AGENT);
                int f6 = __hip_atomic_load(&flag[(rbase +  96)*FSTR], __ATOMIC_RELAXED, __HIP_MEMORY_SCOPE_AGENT);
                int f7 = __hip_atomic_load(&flag[(rbase + 112)*FSTR], __ATOMIC_RELAXED, __HIP_MEMORY_SCOPE_AGENT);
                int mn = min(min(min(f0, f1), min(f2, f3)),
                             min(min(f4, f5), min(f6, f7)));
                if (mn >= s) break;
                __builtin_amdgcn_s_sleep(1);
            }
        }
        asm volatile("" ::: "memory");     // no hoisting panel loads above poll

        floatx4 acc[4];
        #pragma unroll
        for (int nt = 0; nt < 4; ++nt) acc[nt] = (floatx4){0.f,0.f,0.f,0.f};

        const floatx4* a4 = (const floatx4*)(aP + (size_t)s*32768);

        for (int c8 = 0; c8 < 8; ++c8) {
            int i = w*128 + c8*16 + m;
            float Jij = Jr[c8];
            floatx4 av0 = a4[i*16 + q*2],     av1 = a4[i*16 + q*2 + 1];
            floatx4 av2 = a4[i*16 + 8 + q*2], av3 = a4[i*16 + 8 + q*2 + 1];
            floatx4 x0, x1, x2, x3;
            #pragma unroll
            for (int e = 0; e < 4; ++e) {
                x0[e] = fmaxf(fmaf(Jij, wva[e], av0[e]) + cva[e], 0.f);
                x1[e] = fmaxf(fmaf(Jij, wvb[e], av1[e]) + cvb[e], 0.f);
                x2[e] = fmaxf(fmaf(Jij, wvc[e], av2[e]) + cvc[e], 0.f);
                x3[e] = fmaxf(fmaf(Jij, wvd[e], av3[e]) + cvd[e], 0.f);
            }
            union { short8 s; unsigned u[4]; } fa0, fa1;
            fa0.u[0] = pk2bf(x0[0], x0[1]); fa0.u[1] = pk2bf(x0[2], x0[3]);
            fa0.u[2] = pk2bf(x1[0], x1[1]); fa0.u[3] = pk2bf(x1[2], x1[3]);
            fa1.u[0] = pk2bf(x2[0], x2[1]); fa1.u[1] = pk2bf(x2[2], x2[3]);
            fa1.u[2] = pk2bf(x3[0], x3[1]); fa1.u[3] = pk2bf(x3[2], x3[3]);
            #pragma unroll
            for (int nt = 0; nt < 4; ++nt) {
                floatx4 d = {0.f,0.f,0.f,0.f};
                d = __builtin_amdgcn_mfma_f32_16x16x32_bf16(fa0.s, bfw[nt][0], d, 0, 0, 0);
                d = __builtin_amdgcn_mfma_f32_16x16x32_bf16(fa1.s, bfw[nt][1], d, 0, 0, 0);
                #pragma unroll
                for (int r = 0; r < 4; ++r)
                    acc[nt][r] += fmaxf(d[r] + b2n[nt], 0.f);
            }
        }

        // reduce rows within wave, stage h into smGin
        #pragma unroll
        for (int nt = 0; nt < 4; ++nt) {
            float v = acc[nt][0] + acc[nt][1] + acc[nt][2] + acc[nt][3];
            v += __shfl_xor(v, 16);
            v += __shfl_xor(v, 32);
            if (l < 16) smWave[w][nt*16 + l] = v;
        }
        if (tid < 16) smGin[tid] = smH[tid];
        __syncthreads();
        if (tid < 64) smMacc[tid] = smWave[0][tid] + smWave[1][tid]
                                  + smWave[2][tid] + smWave[3][tid];
        __syncthreads();

        // msg = W3 @ macc + 512*b3
        {
            int o = tid >> 3, p = tid & 7;
            const floatx4* W3v = (const floatx4*)W3;
            floatx4 wv0 = W3v[o*16 + p*2], wv1 = W3v[o*16 + p*2 + 1];
            float part = 0.f;
            #pragma unroll
            for (int e = 0; e < 4; ++e) {
                part = fmaf(wv0[e], smMacc[p*8 + e], part);
                part = fmaf(wv1[e], smMacc[p*8 + 4 + e], part);
            }
            part += __shfl_xor(part, 1);
            part += __shfl_xor(part, 2);
            part += __shfl_xor(part, 4);
            if (p == 0) smGin[16 + o] = part + 512.f * b3[o];
        }
        __syncthreads();

        // GRU gates
        if (tid < 192) {
            int o = tid >> 2, p = tid & 3;
            const floatx4* Wv = (const floatx4*)W_ih;
            floatx4 w0 = Wv[o*12 + p*3], w1 = Wv[o*12 + p*3 + 1], w2 = Wv[o*12 + p*3 + 2];
            int k0 = p*12;
            float part = 0.f;
            #pragma unroll
            for (int e = 0; e < 4; ++e) {
                part = fmaf(w0[e], smGin[k0 + e], part);
                part = fmaf(w1[e], smGin[k0 + 4 + e], part);
                part = fmaf(w2[e], smGin[k0 + 8 + e], part);
            }
            part += __shfl_xor(part, 1);
            part += __shfl_xor(part, 2);
            if (p == 0) smGi[o] = part + b_ih[o];
        } else if (tid < 240) {
            int o = tid - 192;
            const floatx4* Wv = (const floatx4*)W_hh;
            floatx4 w0 = Wv[o*4], w1 = Wv[o*4+1], w2 = Wv[o*4+2], w3 = Wv[o*4+3];
            float s2 = b_hh[o];
            #pragma unroll
            for (int e = 0; e < 4; ++e) {
                s2 = fmaf(w0[e], smGin[e],      s2);
                s2 = fmaf(w1[e], smGin[4 + e],  s2);
                s2 = fmaf(w2[e], smGin[8 + e],  s2);
                s2 = fmaf(w3[e], smGin[12 + e], s2);
            }
            smGh[o] = s2;
        }
        __syncthreads();

        if (tid < 16) {
            float r = 1.f / (1.f + __expf(-(smGi[tid] + smGh[tid])));
            float z = 1.f / (1.f + __expf(-(smGi[16+tid] + smGh[16+tid])));
            float n = tanhf(smGi[32+tid] + r * smGh[32+tid]);
            float hn = (1.f - z)*n + z*smGin[tid];
            smH[tid] = hn;
        }
        __syncthreads();

        if (!last) {
            if (tid < 128) {
                int o = tid & 63, sel = tid >> 6;
                const floatx4* Wv = (const floatx4*)(sel ? &smW1hj[0][0] : &smW1hi[0][0]);
                floatx4 w0 = Wv[o*4], w1 = Wv[o*4+1], w2 = Wv[o*4+2], w3 = Wv[o*4+3];
                float sacc = 0.f;
                #pragma unroll
                for (int e = 0; e < 4; ++e) {
                    sacc = fmaf(w0[e], smH[e],      sacc);
                    sacc = fmaf(w1[e], smH[4 + e],  sacc);
                    sacc = fmaf(w2[e], smH[8 + e],  sacc);
                    sacc = fmaf(w3[e], smH[12 + e], sacc);
                }
                if (sel == 0) {
                    // publish next panel row straight to the coherent point
                    __hip_atomic_store(&aP[(size_t)(s+1)*32768 + j*64 + o],
                                       sacc + smAbias[o],
                                       __ATOMIC_RELAXED, __HIP_MEMORY_SCOPE_AGENT);
                } else {
                    smC[o] = sacc + smCbias[o];
                }
            }
            if (tid < 64) {   // producer wave: per-wave vmcnt then set flag
                asm volatile("s_waitcnt vmcnt(0)" ::: "memory");
                if (tid == 0)
                    __hip_atomic_store(&flag[j*FSTR], s + 1,
                                       __ATOMIC_RELAXED, __HIP_MEMORY_SCOPE_AGENT);
            }
            __syncthreads();   // protects smC for next iteration's reads
        } else {
            // fused readout for node j
            if (tid < 64) {
                const floatx4* Wv = (const floatx4*)Wr1;
                floatx4 w0 = Wv[tid*4], w1 = Wv[tid*4+1], w2 = Wv[tid*4+2], w3 = Wv[tid*4+3];
                float sacc = br1[tid];
                #pragma unroll
                for (int e = 0; e < 4; ++e) {
                    sacc = fmaf(w0[e], smH[e],      sacc);
                    sacc = fmaf(w1[e], smH[4 + e],  sacc);
                    sacc = fmaf(w2[e], smH[8 + e],  sacc);
                    sacc = fmaf(w3[e], smH[12 + e], sacc);
                }
                smY[tid] = fmaxf(sacc, 0.f);
            }
            __syncthreads();
            {   // y2: 64 outputs x 64 inputs, 4 threads per output
                int o = tid >> 2, p = tid & 3;
                const floatx4* Wv = (const floatx4*)Wr2;
                floatx4 w0 = Wv[o*16 + p*4],     w1 = Wv[o*16 + p*4 + 1];
                floatx4 w2 = Wv[o*16 + p*4 + 2], w3 = Wv[o*16 + p*4 + 3];
                int k0 = p*16;
                float part = 0.f;
                #pragma unroll
                for (int e = 0; e < 4; ++e) {
                    part = fmaf(w0[e], smY[k0 + e],      part);
                    part = fmaf(w1[e], smY[k0 + 4 + e],  part);
                    part = fmaf(w2[e], smY[k0 + 8 + e],  part);
                    part = fmaf(w3[e], smY[k0 + 12 + e], part);
                }
                part += __shfl_xor(part, 1);
                part += __shfl_xor(part, 2);
                __syncthreads();
                if (p == 0) smY[o] = fmaxf(part + br2[o], 0.f);
            }
            __syncthreads();
            if (tid < 128) {
                int ot = tid >> 6, p = tid & 63;
                float part = Wr3[ot*64 + p] * smY[p];
                part += __shfl_xor(part, 1);
                part += __shfl_xor(part, 2);
                part += __shfl_xor(part, 4);
                part += __shfl_xor(part, 8);
                part += __shfl_xor(part, 16);
                part += __shfl_xor(part, 32);
                if (p == 0) smR[ot] = part + br3[ot];
            }
            __syncthreads();
            if (tid == 0) {
                float e0 = 1.f/(1.f + __expf(-smR[0]));
                float e1 = 1.f/(1.f + __expf(-smR[1]));
                float tsum = e0 + e1;
                out[j*2]     = e0/tsum;
                out[j*2 + 1] = e1/tsum;
            }
        }
    }
}

extern "C" void kernel_launch(void* const* d_in, const int* in_sizes, int n_in,
                              void* d_out, int out_size, void* d_ws, size_t ws_size,
                              hipStream_t stream)
{
    const float* J    = (const float*)d_in[0];
    const float* b    = (const float*)d_in[1];
    const float* W1   = (const float*)d_in[2];
    const float* b1   = (const float*)d_in[3];
    const float* W2   = (const float*)d_in[4];
    const float* b2   = (const float*)d_in[5];
    const float* W3   = (const float*)d_in[6];
    const float* b3   = (const float*)d_in[7];
    const float* W_ih = (const float*)d_in[8];
    const float* b_ih = (const float*)d_in[9];
    const float* W_hh = (const float*)d_in[10];
    const float* b_hh = (const float*)d_in[11];
    const float* Wr1  = (const float*)d_in[12];
    const float* br1  = (const float*)d_in[13];
    const float* Wr2  = (const float*)d_in[14];
    const float* br2  = (const float*)d_in[15];
    const float* Wr3  = (const float*)d_in[16];
    const float* br3  = (const float*)d_in[17];
    float* outp = (float*)d_out;

    float* ws = (float*)d_ws;
    float* aP    = ws;                       // 6 * 32768 floats (slot 0 unused)
    int*   flags = (int*)(ws + 6*32768);     // 512 * FSTR ints = 64 KB
    const size_t FLAG_BYTES = 512u * FSTR * sizeof(int);

    // zero the flags (epochs start at 1); stream-ordered, graph-safe
    hipMemsetAsync((void*)flags, 0, FLAG_BYTES, stream);

    // PLAIN launch: 512 blocks x 256 threads = 2 blocks/CU, all co-resident
    // (VGPR capped at 256 by __launch_bounds__(256,2); LDS ~10KB/block).
    hipLaunchKernelGGL(fused4_kernel, dim3(NN), dim3(256), 0, stream,
        J, b, W1, b1, W2, b2, W3, b3, W_ih, b_ih, W_hh, b_hh,
        Wr1, br1, Wr2, br2, Wr3, br3, aP, flags, outp);
}